// Round 11
// baseline (1992.541 us; speedup 1.0000x reference)
//
#include <hip/hip_runtime.h>

typedef _Float16 half8  __attribute__((ext_vector_type(8)));
typedef _Float16 half4_t __attribute__((ext_vector_type(4)));
typedef float    f32x4  __attribute__((ext_vector_type(4)));

static constexpr int BATCH = 16;
static constexpr int NSEQ  = 2048;
static constexpr int DDIM  = 512;
static constexpr int MROWS = BATCH * NSEQ;   // 32768

// workspace layout (bytes): wt 2MB | q 32MB | k 32MB | vt 32MB | xh 32MB = 130MB
static constexpr size_t WT_OFF = 0;
static constexpr size_t Q_OFF  = 2u * 1024 * 1024;
static constexpr size_t K_OFF  = Q_OFF + (size_t)MROWS * DDIM * 2;
static constexpr size_t VT_OFF = K_OFF + (size_t)MROWS * DDIM * 2;
static constexpr size_t XH_OFF = VT_OFF + (size_t)MROWS * DDIM * 2;

// async global->LDS, 16B per lane, dest = uniform base + lane*16
typedef const __attribute__((address_space(1))) void cg_void;
typedef __attribute__((address_space(3))) void lds_void;
__device__ __forceinline__ void gload_lds16(const void* g, void* l) {
    __builtin_amdgcn_global_load_lds((cg_void*)g, (lds_void*)l, 16, 0, 0);
}

// ---------------- K0a: x fp32 -> fp16 ---------------------------------------
__global__ void xconv(const float* __restrict__ x, _Float16* __restrict__ xh) {
    size_t base = ((size_t)blockIdx.x * 256 + threadIdx.x) * 8;
    float4 a = *(const float4*)(x + base);
    float4 b = *(const float4*)(x + base + 4);
    half8 h;
    h[0] = (_Float16)a.x; h[1] = (_Float16)a.y; h[2] = (_Float16)a.z; h[3] = (_Float16)a.w;
    h[4] = (_Float16)b.x; h[5] = (_Float16)b.y; h[6] = (_Float16)b.z; h[7] = (_Float16)b.w;
    *(half8*)(xh + base) = h;
}

// ---------------- K0b: weight fp32 -> fp16 transposed, LDS tile --------------
// wt[pj*512 + n][e] = W_pj[e][n]; coalesced read rows, coalesced write rows.
__global__ void wt_prep(const float* __restrict__ Wq, const float* __restrict__ Wk,
                        const float* __restrict__ Wv, _Float16* __restrict__ wt) {
    __shared__ float T[64][65];
    const int pj = blockIdx.z;
    const float* W = (pj == 0) ? Wq : (pj == 1 ? Wk : Wv);
    const int n0 = blockIdx.x * 64, e0 = blockIdx.y * 64;
    const int tid = threadIdx.x;
    #pragma unroll
    for (int i = 0; i < 4; ++i) {
        int c = tid + i * 256;              // 1024 float4 chunks
        int row = c >> 4, o4 = c & 15;      // row = e, o4*4 = n offset
        float4 v = *(const float4*)(W + (size_t)(e0 + row) * 512 + n0 + o4 * 4);
        T[row][o4 * 4 + 0] = v.x; T[row][o4 * 4 + 1] = v.y;
        T[row][o4 * 4 + 2] = v.z; T[row][o4 * 4 + 3] = v.w;
    }
    __syncthreads();
    #pragma unroll
    for (int i = 0; i < 2; ++i) {
        int c = tid + i * 256;              // 512 16B chunks
        int nr = c >> 3, o = c & 7;         // nr = n row, o*8 = e offset
        half8 h;
        #pragma unroll
        for (int j = 0; j < 8; ++j) h[j] = (_Float16)T[o * 8 + j][nr];
        *(half8*)(wt + (size_t)(pj * 512 + n0 + nr) * 512 + e0 + o * 8) = h;
    }
}

// ---------------- K1: fused QKV GEMM (128x128, dbuf, V stored transposed) ---
__global__ __launch_bounds__(256, 2) void qkv_gemm(
        const _Float16* __restrict__ xh, const _Float16* __restrict__ wt,
        const float* __restrict__ bq, const float* __restrict__ bk,
        const float* __restrict__ bv, _Float16* __restrict__ qk_out,
        _Float16* __restrict__ vt) {
    __shared__ alignas(16) char Asw[2][128 * 128];
    __shared__ alignas(16) char Bsw[2][128 * 128];
    const int tid  = threadIdx.x;
    const int lane = tid & 63;
    const int wid  = tid >> 6;
    const int lg = lane >> 4, lm = lane & 15;
    const int wr = wid >> 1, wc = wid & 1;

    const int id = blockIdx.x;
    const int wg = (id & 7) * 384 + (id >> 3);
    const int bm = wg & 255, bn = wg >> 8;
    const int m0 = bm * 128, n0 = bn * 128;
    const int proj = n0 >> 9;
    const float* bias = (proj == 0) ? bq : (proj == 1 ? bk : bv);

    f32x4 acc[4][4] = {};

    const int rloc = (lane >> 3);
    const int p    = lane & 7;

    auto STAGE = [&](int kk, int bb) {
        #pragma unroll
        for (int i = 0; i < 4; ++i) {
            int g = wid * 4 + i;
            int r = g * 8 + rloc;
            gload_lds16(xh + (size_t)(m0 + r) * 512 + kk + ((p ^ (r & 7)) * 8),
                        Asw[bb] + g * 1024);
            gload_lds16(wt + (size_t)(n0 + r) * 512 + kk + ((p ^ (r & 7)) * 8),
                        Bsw[bb] + g * 1024);
        }
    };

    STAGE(0, 0);
    for (int ks = 0; ks < 8; ++ks) {
        __syncthreads();
        if (ks < 7) STAGE((ks + 1) * 64, (ks & 1) ^ 1);
        const char* Ab = Asw[ks & 1];
        const char* Bb = Bsw[ks & 1];
        #pragma unroll
        for (int es = 0; es < 2; ++es) {
            half8 a[4], b[4];
            #pragma unroll
            for (int i = 0; i < 4; ++i) {
                int row = wr * 64 + i * 16 + lm;
                a[i] = *(const half8*)(Ab + row * 128 + (((es * 4 + lg) ^ (row & 7)) * 16));
            }
            #pragma unroll
            for (int j = 0; j < 4; ++j) {
                int row = wc * 64 + j * 16 + lm;
                b[j] = *(const half8*)(Bb + row * 128 + (((es * 4 + lg) ^ (row & 7)) * 16));
            }
            #pragma unroll
            for (int i = 0; i < 4; ++i)
                #pragma unroll
                for (int j = 0; j < 4; ++j)
                    acc[i][j] = __builtin_amdgcn_mfma_f32_16x16x32_f16(a[i], b[j], acc[i][j], 0, 0, 0);
        }
    }
    if (proj < 2) {
        const size_t pb = (size_t)proj * MROWS * DDIM;
        #pragma unroll
        for (int i = 0; i < 4; ++i) {
            #pragma unroll
            for (int j = 0; j < 4; ++j) {
                int mg = m0 + wr * 64 + i * 16 + lg * 4;
                int c  = (n0 & 511) + wc * 64 + j * 16 + lm;
                float bb = bias[c];
                #pragma unroll
                for (int r = 0; r < 4; ++r)
                    qk_out[pb + (size_t)(mg + r) * DDIM + c] = (_Float16)(acc[i][j][r] + bb);
            }
        }
    } else {
        // V: store transposed vt[b][e][n]
        _Float16* vtb = vt + (size_t)(m0 >> 11) * 512 * NSEQ;
        #pragma unroll
        for (int i = 0; i < 4; ++i) {
            #pragma unroll
            for (int j = 0; j < 4; ++j) {
                int nn = (m0 & 2047) + wr * 64 + i * 16 + lg * 4;
                int e  = (n0 & 511) + wc * 64 + j * 16 + lm;
                float bb = bias[e];
                half4_t h;
                #pragma unroll
                for (int r = 0; r < 4; ++r) h[r] = (_Float16)(acc[i][j][r] + bb);
                *(half4_t*)(vtb + (size_t)e * NSEQ + nn) = h;
            }
        }
    }
}

// ---------------- K3: flash attention, swapped QK^T, single-buffered KV ------
// block = 128 q-rows (8 waves x 16), 64 K-tiles of 32 keys, 77.8KB LDS -> 2 blocks/CU.
// alpha: K[t] resident, Vs free -> stage V[t]; beta: V[t] resident, Ks free -> stage K[t+1].
__global__ __launch_bounds__(512, 4) void attn(
        const _Float16* __restrict__ q, const _Float16* __restrict__ k,
        const _Float16* __restrict__ vt, float* __restrict__ out) {
    __shared__ alignas(16) char Ks[32768];            // [key][512 f16], granule ^ (key&7)
    __shared__ alignas(16) char Vs[32768];            // [e][32 f16],   granule ^ ((e>>1)&3)
    __shared__ alignas(16) _Float16 Pl[8][16][48];    // per-wave P relayout

    const int tid = threadIdx.x, lane = tid & 63, wid = tid >> 6;   // wid 0..7
    const int lg = lane >> 4, lm = lane & 15;

    // XCD-aware: blocks of batch b land on XCD (b&7) -> K/V L2-resident
    const int id = blockIdx.x;                  // 256 blocks
    const int b  = (id & 7) | ((id >> 7) << 3);
    const int n0 = ((id >> 3) & 15) * 128;

    // Q fragments: rows = n0 + wid*16 + lm (valid as MFMA B-operand: col=lm)
    const _Float16* qrow = q + ((size_t)(b * NSEQ + n0 + wid * 16 + lm)) * 512;
    half8 qf[16];
    #pragma unroll
    for (int es = 0; es < 16; ++es)
        qf[es] = *(const half8*)(qrow + es * 32 + lg * 8);

    f32x4 o[32] = {};
    float m_r = -__builtin_inff(), l_r = 0.f;   // scalar: this lane's q-row = lm

    const _Float16* kb  = k  + (size_t)b * NSEQ * 512;
    const _Float16* vtb = vt + (size_t)b * 512 * NSEQ;

    // staging offsets: chunk i covers 1KB; R = wid*4+i (8 waves x 4 = 32 chunks)
    int koff[4], voff[4];
    #pragma unroll
    for (int i = 0; i < 4; ++i) {
        int R = wid * 4 + i;
        koff[i] = R * 512 + ((lane ^ (R & 7)) * 8);
        voff[i] = (R * 16 + (lane >> 2)) * NSEQ + (((lane & 3) ^ ((lane >> 3) & 3)) * 8);
    }

    auto STAGE_K = [&](int tt) {
        const _Float16* ks = kb + (size_t)tt * (32 * 512);
        #pragma unroll
        for (int i = 0; i < 4; ++i)
            gload_lds16(ks + koff[i], Ks + (wid * 4 + i) * 1024);
    };
    auto STAGE_V = [&](int tt) {
        const _Float16* vs = vtb + (size_t)tt * 32;
        #pragma unroll
        for (int i = 0; i < 4; ++i)
            gload_lds16(vs + voff[i], Vs + (wid * 4 + i) * 1024);
    };

    STAGE_K(0);
    for (int t = 0; t < 64; ++t) {
        __syncthreads();                 // alpha: K[t] resident; Vs free
        STAGE_V(t);                      // flies under QK+softmax

        // swapped QK^T: s = K x Q -> C[key][qrow]; lane owns q-row lm,
        // keys lg*4+r (s0) and 16+lg*4+r (s1)
        f32x4 s0 = {}, s1 = {};
        #pragma unroll
        for (int es = 0; es < 16; ++es) {
            const int off = es * 64 + lg * 16;
            half8 k0 = *(const half8*)(Ks + lm * 1024 + (off ^ ((lm & 7) << 4)));
            half8 k1 = *(const half8*)(Ks + (lm + 16) * 1024 + (off ^ ((lm & 7) << 4)));
            s0 = __builtin_amdgcn_mfma_f32_16x16x32_f16(k0, qf[es], s0, 0, 0, 0);
            s1 = __builtin_amdgcn_mfma_f32_16x16x32_f16(k1, qf[es], s1, 0, 0, 0);
        }

        // lane-local softmax for q-row lm: 8 local scores + 2 shfl
        float tm = fmaxf(fmaxf(fmaxf(s0[0], s0[1]), fmaxf(s0[2], s0[3])),
                         fmaxf(fmaxf(s1[0], s1[1]), fmaxf(s1[2], s1[3])));
        tm = fmaxf(tm, __shfl_xor(tm, 16));
        tm = fmaxf(tm, __shfl_xor(tm, 32));
        float mn = fmaxf(m_r, tm);
        const bool skip = __all((int)(mn - m_r <= 8.f));   // T13 defer-max
        float use_m, sc;
        if (skip) { use_m = m_r; sc = 1.f; }
        else      { use_m = mn; sc = __expf(m_r - mn); m_r = mn; }

        float p0[4], p1[4];
        #pragma unroll
        for (int r = 0; r < 4; ++r) {
            p0[r] = __expf(s0[r] - use_m);
            p1[r] = __expf(s1[r] - use_m);
        }
        float rsum = (p0[0] + p0[1]) + (p0[2] + p0[3]) +
                     (p1[0] + p1[1]) + (p1[2] + p1[3]);
        rsum += __shfl_xor(rsum, 16);
        rsum += __shfl_xor(rsum, 32);
        l_r = l_r * sc + rsum;

        // packed P write: row = q-row lm (b64, conflict-free), same-wave read
        half4_t h0, h1;
        #pragma unroll
        for (int r = 0; r < 4; ++r) { h0[r] = (_Float16)p0[r]; h1[r] = (_Float16)p1[r]; }
        *(half4_t*)&Pl[wid][lm][lg * 4]      = h0;
        *(half4_t*)&Pl[wid][lm][16 + lg * 4] = h1;
        half8 pf = *(const half8*)&Pl[wid][lm][lg * 8];

        __syncthreads();                 // beta: V[t] resident; Ks consumed
        if (t < 63) STAGE_K(t + 1);      // flies under rescale+PV

        if (!skip) {                     // rescale O; factors at lanes lm = row
            float scq[4];
            #pragma unroll
            for (int r = 0; r < 4; ++r) scq[r] = __shfl(sc, lg * 4 + r);
            #pragma unroll
            for (int eg = 0; eg < 32; ++eg)
                #pragma unroll
                for (int r = 0; r < 4; ++r) o[eg][r] *= scq[r];
        }

        // PV: O[qrow][e] += P x V
        #pragma unroll
        for (int eg = 0; eg < 32; ++eg) {
            int e = eg * 16 + lm;
            half8 vf = *(const half8*)(Vs + e * 64 + ((lg ^ ((lm >> 1) & 3)) << 4));
            o[eg] = __builtin_amdgcn_mfma_f32_16x16x32_f16(pf, vf, o[eg], 0, 0, 0);
        }
    }

    // epilogue: denominators for output rows lg*4+r live at lanes lm = row
    float inv[4];
    #pragma unroll
    for (int r = 0; r < 4; ++r) inv[r] = 1.f / __shfl(l_r, lg * 4 + r);
    float* ob = out + ((size_t)(b * NSEQ + n0 + wid * 16 + lg * 4)) * 512;
    #pragma unroll
    for (int eg = 0; eg < 32; ++eg)
        #pragma unroll
        for (int r = 0; r < 4; ++r)
            ob[(size_t)r * 512 + eg * 16 + lm] = o[eg][r] * inv[r];
}

// ---------------- launcher ---------------------------------------------------
extern "C" void kernel_launch(void* const* d_in, const int* in_sizes, int n_in,
                              void* d_out, int out_size, void* d_ws, size_t ws_size,
                              hipStream_t stream) {
    const float* x  = (const float*)d_in[0];
    const float* Wq = (const float*)d_in[1];
    const float* bq = (const float*)d_in[2];
    const float* Wk = (const float*)d_in[3];
    const float* bk = (const float*)d_in[4];
    const float* Wv = (const float*)d_in[5];
    const float* bv = (const float*)d_in[6];
    float* out = (float*)d_out;
    char* ws = (char*)d_ws;

    _Float16* wt   = (_Float16*)(ws + WT_OFF);
    _Float16* qbuf = (_Float16*)(ws + Q_OFF);
    _Float16* kbuf = (_Float16*)(ws + K_OFF);
    _Float16* vt   = (_Float16*)(ws + VT_OFF);
    _Float16* xh   = (_Float16*)(ws + XH_OFF);

    xconv<<<8192, 256, 0, stream>>>(x, xh);
    wt_prep<<<dim3(8, 8, 3), 256, 0, stream>>>(Wq, Wk, Wv, wt);
    qkv_gemm<<<3072, 256, 0, stream>>>(xh, wt, bq, bk, bv, qbuf, vt);
    attn<<<256, 512, 0, stream>>>(qbuf, kbuf, vt, out);
}